// Round 4
// baseline (71.090 us; speedup 1.0000x reference)
//
#include <hip/hip_runtime.h>

// YOLO layer: x (32, 255, 76, 76) fp32 -> out (32, 76*76*3, 85) fp32
// out flat = b*(76*76*255) + h*(76*255) + w*255 + (a*85 + attr)
//          = f(x[b][a*85+attr][h][w])
//   attr 0: (sigmoid(v) + w) * 8     attr 2: exp(v) * {10,16,33}[a]
//   attr 1: (sigmoid(v) + h) * 8     attr 3: exp(v) * {13,30,23}[a]
//   else  : sigmoid(v)
//
// PERSISTENT SINGLE-BUFFER PIPELINE, 2 blocks/CU (512 blocks, 4-5 tiles each).
// Round-4 change: LINE-ALIGNED STORE STREAM. Tile output base = t*77520 B,
// 77520 % 64 == 16, so round-3's wave stores straddled 2 cache lines each;
// with nt eviction + two interleaved store streams per CU the straddle lines
// were written to HBM twice (WRITE_SIZE 222 MB vs 188.5 ideal, +RMW fetches).
// Shift the stream by s = (-t) & 3 f4s (4845 % 4 == 1): head (<=3 f4) by
// tid < s, bulk at i = s + tid + k*1024 -> every wave-store covers exactly
// 16 full lines. Only the 2 tile-edge lines stay partial (complemented by the
// adjacent tile: same XCD, same epoch).

typedef float f4 __attribute__((ext_vector_type(4)));

constexpr int NB = 32;
constexpr int NH = 76;
constexpr int NW = 76;
constexpr int C = 255;                 // 3 anchors * 85
constexpr int ROW_F4 = NW / 4;         // 19 f4 per input row
constexpr int BLK_F4 = C * ROW_F4;     // 4845 f4 per tile
constexpr int TILES = NB * NH;         // 2432
constexpr int NTH = 1024;
constexpr int KMAX = 5;                // ceil(4845/1024)
constexpr int TAIL = BLK_F4 - 4 * NTH; // 749 (k==4 active threads, load side)
constexpr int GRID = 512;              // 2 blocks per CU
constexpr int NXCD = 8;
constexpr int PER_XCD = TILES / NXCD;        // 304
constexpr int BLKS_PER_XCD = GRID / NXCD;    // 64
constexpr float STRIDE = 8.0f;

__device__ __forceinline__ float sigmoidf_(float v) {
    return 1.0f / (1.0f + __expf(-v));
}

__global__ __launch_bounds__(NTH, 8) void yolo_kernel(const f4* __restrict__ x4,
                                                      f4* __restrict__ out4) {
    __shared__ f4 buf[BLK_F4];         // 77520 B -> 2 blocks/CU

    const int tid = threadIdx.x;

    // ---- thread-invariant per-k geometry & transform descriptors ----
    int offk[KMAX];      // input f4 offset within tile: row*(NH*ROW_F4)+c
    int basek[KMAX];     // LDS scatter base (floats): 4*c*C + row
    int modek[KMAX];     // 0 plain sigmoid, 1 bx, 2 by, 3 exp*scale
    float auxk[KMAX];    // mode 1: w base; mode 3: anchor scale

#pragma unroll
    for (int k = 0; k < KMAX; ++k) {
        const int i = tid + k * NTH;
        const int ii = (k < 4 || tid < TAIL) ? i : 0;
        const int row = ii / ROW_F4;           // channel 0..254
        const int c = ii - row * ROW_F4;       // f4 index along w
        offk[k] = row * (NH * ROW_F4) + c;
        basek[k] = 4 * c * C + row;
        const int a = (row >= 170) ? 2 : ((row >= 85) ? 1 : 0);
        const int attr = row - 85 * a;
        int mode = 0;
        float aux = (float)(4 * c);            // default: w base (mode 1)
        if (attr == 0) mode = 1;
        else if (attr == 1) mode = 2;
        else if (attr == 2) { mode = 3; aux = (a == 0) ? 10.f : ((a == 1) ? 16.f : 33.f); }
        else if (attr == 3) { mode = 3; aux = (a == 0) ? 13.f : ((a == 1) ? 30.f : 23.f); }
        modek[k] = mode;
        auxk[k] = aux;
    }

    // ---- XCD-contiguous tile assignment ----
    const int x = blockIdx.x & (NXCD - 1);     // XCD (dispatch round-robin)
    const int j = blockIdx.x >> 3;             // block index within XCD, 0..63
    const int base_t = x * PER_XCD;
    const int ntile = 4 + (j < (PER_XCD - 4 * BLKS_PER_XCD) ? 1 : 0);  // 4 or 5

    f4 stage[KMAX];

    auto issue = [&](int t) {
        const int b = t / NH;
        const int h = t - b * NH;
        const size_t inb = (size_t)b * (C * NH * ROW_F4) + (size_t)h * ROW_F4;
#pragma unroll
        for (int k = 0; k < KMAX; ++k)
            if (k < 4 || tid < TAIL) stage[k] = x4[inb + offk[k]];
    };

    int t = base_t + j;                        // tile for idx 0
    issue(t);
    int idx = 0;
    float* __restrict__ tb = (float*)buf;

    while (true) {
        // ---- transform stage in place (waits on global loads) ----
        const float hf = (float)(t % NH);
#pragma unroll
        for (int k = 0; k < KMAX; ++k) {
            if (!(k < 4 || tid < TAIL)) continue;
            const f4 v = stage[k];
            f4 r;
            if (modek[k] == 3) {
                r.x = __expf(v.x) * auxk[k];
                r.y = __expf(v.y) * auxk[k];
                r.z = __expf(v.z) * auxk[k];
                r.w = __expf(v.w) * auxk[k];
            } else {
                r.x = sigmoidf_(v.x);
                r.y = sigmoidf_(v.y);
                r.z = sigmoidf_(v.z);
                r.w = sigmoidf_(v.w);
                if (modek[k] == 1) {
                    r.x = (r.x + auxk[k]) * STRIDE;
                    r.y = (r.y + auxk[k] + 1.0f) * STRIDE;
                    r.z = (r.z + auxk[k] + 2.0f) * STRIDE;
                    r.w = (r.w + auxk[k] + 3.0f) * STRIDE;
                } else if (modek[k] == 2) {
                    r.x = (r.x + hf) * STRIDE;
                    r.y = (r.y + hf) * STRIDE;
                    r.z = (r.z + hf) * STRIDE;
                    r.w = (r.w + hf) * STRIDE;
                }
            }
            stage[k] = r;
        }

        if (idx > 0) __syncthreads();          // prev store-phase reads done

        // ---- scatter-transpose transformed values into LDS ----
#pragma unroll
        for (int k = 0; k < KMAX; ++k) {
            if (!(k < 4 || tid < TAIL)) continue;
            const f4 r = stage[k];
            const int base = basek[k];
            tb[base]         = r.x;
            tb[base + C]     = r.y;
            tb[base + 2 * C] = r.z;
            tb[base + 3 * C] = r.w;
        }

        const size_t ob = (size_t)t * BLK_F4;  // f4 units; byte base % 64 != 0
        const int s = (-t) & 3;                // shift so stream is line-aligned
        ++idx;
        const bool more = (idx < ntile);
        if (more) {                            // issue next tile's loads now:
            t = base_t + idx * BLKS_PER_XCD + j;
            issue(t);                          // latency hides under store phase
        }

        __syncthreads();                       // LDS writes visible

        // ---- line-aligned streaming store ----
        if (tid < s)                           // head: <=3 f4 before alignment
            __builtin_nontemporal_store(buf[tid], &out4[ob + tid]);
#pragma unroll
        for (int k = 0; k < 4; ++k) {          // bulk: every wave = 16 lines
            const int i = s + tid + k * NTH;
            __builtin_nontemporal_store(buf[i], &out4[ob + i]);
        }
        {
            const int i = s + tid + 4 * NTH;   // tail
            if (i < BLK_F4)
                __builtin_nontemporal_store(buf[i], &out4[ob + i]);
        }

        if (!more) break;
    }
}

extern "C" void kernel_launch(void* const* d_in, const int* in_sizes, int n_in,
                              void* d_out, int out_size, void* d_ws, size_t ws_size,
                              hipStream_t stream) {
    const f4* x4 = (const f4*)d_in[0];
    f4* out4 = (f4*)d_out;
    yolo_kernel<<<GRID, NTH, 0, stream>>>(x4, out4);
}

// Round 5
// 63.805 us; speedup vs baseline: 1.1142x; 1.1142x over previous
//
#include <hip/hip_runtime.h>

// YOLO layer: x (32, 255, 76, 76) fp32 -> out (32, 76*76*3, 85) fp32
// out flat = b*(76*76*255) + h*(76*255) + w*255 + (a*85 + attr)
//          = f(x[b][a*85+attr][h][w])
//   attr 0: (sigmoid(v) + w) * 8     attr 2: exp(v) * {10,16,33}[a]
//   attr 1: (sigmoid(v) + h) * 8     attr 3: exp(v) * {13,30,23}[a]
//   else  : sigmoid(v)
//
// PERSISTENT SINGLE-BUFFER PIPELINE, 2 blocks/CU (512 blocks, 4-5 tiles each).
// Round-5 change: ELIMINATE SCRATCH SPILL. Round 3/4 kept stage[5] (20 VGPR)
// + 4 descriptor arrays (20 VGPR) under a 64-VGPR cap (launch_bounds 1024,8)
// -> VGPR_Count=32 means the arrays spilled to scratch: ~80 B/thread * 512k
// threads = ~42 MB of scratch writes, matching the WRITE_SIZE anomaly
// (222-228 MB vs 188.5 ideal; round 2, uncapped VGPR=52, had exactly 188).
// Fix: keep only stage[5] + offk[5]; recompute mode/aux/LDS-base inside a
// fused transform+scatter loop, branch-free with ONE transcendental/element:
//   E = exp(attr in {2,3} ? v : -v); sg = 1/(1+E)
//   r = attr in {2,3} ? E*anchor : attr<2 ? (sg + (w|h))*8 : sg
// Round-4's 64 B store-alignment shift is reverted (measured neutral/negative;
// straddle theory falsified).

typedef float f4 __attribute__((ext_vector_type(4)));

constexpr int NB = 32;
constexpr int NH = 76;
constexpr int NW = 76;
constexpr int C = 255;                 // 3 anchors * 85
constexpr int ROW_F4 = NW / 4;         // 19 f4 per input row
constexpr int BLK_F4 = C * ROW_F4;     // 4845 f4 per tile
constexpr int TILES = NB * NH;         // 2432
constexpr int NTH = 1024;
constexpr int KMAX = 5;                // ceil(4845/1024)
constexpr int TAIL = BLK_F4 - 4 * NTH; // 749 (k==4 active threads)
constexpr int GRID = 512;              // 2 blocks per CU
constexpr int NXCD = 8;
constexpr int PER_XCD = TILES / NXCD;        // 304
constexpr int BLKS_PER_XCD = GRID / NXCD;    // 64
constexpr float STRIDE = 8.0f;

__global__ __launch_bounds__(NTH, 8) void yolo_kernel(const f4* __restrict__ x4,
                                                      f4* __restrict__ out4) {
    __shared__ f4 buf[BLK_F4];         // 77520 B -> 2 blocks/CU
    float* __restrict__ tb = (float*)buf;

    const int tid = threadIdx.x;

    // ---- only persistent per-thread array: tile-invariant input offsets ----
    int offk[KMAX];
#pragma unroll
    for (int k = 0; k < KMAX; ++k) {
        const int i = tid + k * NTH;
        const int ii = (k < 4 || tid < TAIL) ? i : 0;
        const int row = ii / ROW_F4;           // channel 0..254
        const int c = ii - row * ROW_F4;       // f4 index along w
        offk[k] = row * (NH * ROW_F4) + c;
    }

    // ---- XCD-contiguous tile assignment ----
    const int x = blockIdx.x & (NXCD - 1);     // XCD (dispatch round-robin)
    const int j = blockIdx.x >> 3;             // block index within XCD, 0..63
    const int base_t = x * PER_XCD;
    const int ntile = 4 + (j < (PER_XCD - 4 * BLKS_PER_XCD) ? 1 : 0);  // 4 or 5

    f4 stage[KMAX];

    auto issue = [&](int t) {
        const int b = t / NH;
        const int h = t - b * NH;
        const size_t inb = (size_t)b * (C * NH * ROW_F4) + (size_t)h * ROW_F4;
#pragma unroll
        for (int k = 0; k < KMAX; ++k)
            if (k < 4 || tid < TAIL) stage[k] = x4[inb + offk[k]];
    };

    int t = base_t + j;                        // tile for idx 0
    issue(t);
    int idx = 0;

    while (true) {
        const float hf = (float)(t % NH);      // block-uniform

        if (idx > 0) __syncthreads();          // prev store-phase reads done

        // ---- fused transform + scatter (descriptors recomputed, no arrays) ----
#pragma unroll
        for (int k = 0; k < KMAX; ++k) {
            if (!(k < 4 || tid < TAIL)) continue;
            const int i = tid + k * NTH;
            const int row = i / ROW_F4;        // channel 0..254
            const int c = i - row * ROW_F4;
            const int a = (row >= 85 ? 1 : 0) + (row >= 170 ? 1 : 0);
            const int attr = row - 85 * a;
            const bool m3 = (attr == 2) || (attr == 3);
            const bool m12 = attr < 2;
            const float aw = (a == 0) ? 10.f : ((a == 1) ? 16.f : 33.f);
            const float ah = (a == 0) ? 13.f : ((a == 1) ? 30.f : 23.f);
            const float aux3 = (attr == 2) ? aw : ah;
            const float w0 = (float)(4 * c);
            const int base = 4 * c * C + row;  // tile[w=4c+e][ch=row]

            const f4 v = stage[k];
            f4 r;
#pragma unroll
            for (int e = 0; e < 4; ++e) {
                const float ve = v[e];
                const float E = __expf(m3 ? ve : -ve);  // one exp per element
                const float sg = 1.0f / (1.0f + E);
                const float add = (attr == 0) ? (w0 + (float)e) : hf;
                float o = m3 ? (E * aux3) : sg;
                if (m12) o = (sg + add) * STRIDE;
                r[e] = o;
            }
            tb[base]         = r.x;
            tb[base + C]     = r.y;
            tb[base + 2 * C] = r.z;
            tb[base + 3 * C] = r.w;
        }

        const size_t ob = (size_t)t * BLK_F4;
        ++idx;
        const bool more = (idx < ntile);
        if (more) {                            // issue next tile's loads now:
            t = base_t + idx * BLKS_PER_XCD + j;
            issue(t);                          // latency hides under store phase
        }

        __syncthreads();                       // LDS writes visible

        // ---- pure streaming store: contiguous b128 reads + nt stores ----
#pragma unroll
        for (int k = 0; k < KMAX; ++k) {
            const int i = tid + k * NTH;
            if (k < 4 || tid < TAIL)
                __builtin_nontemporal_store(buf[i], &out4[ob + i]);
        }

        if (!more) break;
    }
}

extern "C" void kernel_launch(void* const* d_in, const int* in_sizes, int n_in,
                              void* d_out, int out_size, void* d_ws, size_t ws_size,
                              hipStream_t stream) {
    const f4* x4 = (const f4*)d_in[0];
    f4* out4 = (f4*)d_out;
    yolo_kernel<<<GRID, NTH, 0, stream>>>(x4, out4);
}